// Round 2
// baseline (203.266 us; speedup 1.0000x reference)
//
#include <hip/hip_runtime.h>

#define B_ 32
#define T_ 512
#define D_ 256
#define P_ 8
#define BT (B_*T_)
#define KT 32
#define NKT (D_/KT)
#define RPW 16           // rows per wave
#define RPB 64           // rows per block (4 waves)

typedef float f4 __attribute__((ext_vector_type(4)));

// ---------------- kernel 0: W1 [e][d] -> w1t [d][e] ----------------
__global__ void k_transpose(const float* __restrict__ W1, float* __restrict__ w1t) {
  int d = blockIdx.x;
  int e = threadIdx.x;
  w1t[d * D_ + e] = W1[e * D_ + d];
}

// ---------------- kernel 1: fused GEMM1 + GEMM2 + argmax -> dur ----------------
// 256 blocks x 256 threads (4 waves). Block = 64 rows, wave = 16 rows.
// W k-tiles double-buffered in LDS; raw s_barrier + counted vmcnt (no drain).
__global__ __launch_bounds__(256, 1) void k_dur(
    const float* __restrict__ x, const float* __restrict__ w1t,
    const float* __restrict__ b1, const float* __restrict__ W2,
    const float* __restrict__ b2, int* __restrict__ dur)
{
  __shared__ float xs[RPB][D_];       // 64 KB, x rows (staged once)
  __shared__ float wst[2][KT][D_];    // 64 KB, W1^T k-tile double buffer

  const int tid  = threadIdx.x;
  const int lane = tid & 63;
  const int wave = tid >> 6;
  const int row0 = blockIdx.x * RPB;

  // stage x rows (16 per wave), oldest in vmcnt FIFO
  for (int i = 0; i < RPW; ++i) {
    int r = wave * RPW + i;
    const float* g = x + (size_t)(row0 + r) * D_ + lane * 4;
    __builtin_amdgcn_global_load_lds(
        (const __attribute__((address_space(1))) void*)g,
        (__attribute__((address_space(3))) void*)&xs[r][0], 16, 0, 0);
  }
  // stage W k-tiles 0 and 1 (8 rows per wave each)
  for (int bu = 0; bu < 2; ++bu)
    for (int i = 0; i < 8; ++i) {
      int dd = wave * 8 + i;
      const float* g = w1t + (size_t)(bu * KT + dd) * D_ + lane * 4;
      __builtin_amdgcn_global_load_lds(
          (const __attribute__((address_space(1))) void*)g,
          (__attribute__((address_space(3))) void*)&wst[bu][dd][0], 16, 0, 0);
    }
  // wait: x + tile0 landed (tile1's 8 loads may stay in flight)
  asm volatile("s_waitcnt vmcnt(8)" ::: "memory");
  __builtin_amdgcn_s_barrier();
  __builtin_amdgcn_sched_barrier(0);

  f4 b1v = *(const f4*)(b1 + lane * 4);
  f4 acc[RPW];
  #pragma unroll
  for (int i = 0; i < RPW; ++i) acc[i] = b1v;

  for (int kt = 0; kt < NKT; ++kt) {
    const int cur = kt & 1;
    f4 loc[RPW];      // per-k-tile partials: keeps summation order identical to R1
    #pragma unroll
    for (int i = 0; i < RPW; ++i) loc[i] = (f4){0.f, 0.f, 0.f, 0.f};

    #pragma unroll
    for (int dq = 0; dq < KT / 4; ++dq) {
      f4 wv[4];
      #pragma unroll
      for (int j = 0; j < 4; ++j) wv[j] = *(const f4*)&wst[cur][dq * 4 + j][lane * 4];
      #pragma unroll
      for (int i = 0; i < RPW; ++i) {
        f4 xv = *(const f4*)&xs[wave * RPW + i][kt * KT + dq * 4];  // wave-uniform broadcast
        loc[i] += xv.x * wv[0];
        loc[i] += xv.y * wv[1];
        loc[i] += xv.z * wv[2];
        loc[i] += xv.w * wv[3];
      }
    }
    #pragma unroll
    for (int i = 0; i < RPW; ++i) acc[i] += loc[i];

    if (kt < NKT - 1) {
      __builtin_amdgcn_s_barrier();          // all waves done reading wst[cur]
      __builtin_amdgcn_sched_barrier(0);
      if (kt + 2 < NKT) {
        // prefetch k-tile kt+2 into the buffer we just finished reading
        for (int i = 0; i < 8; ++i) {
          int dd = wave * 8 + i;
          const float* g = w1t + (size_t)((kt + 2) * KT + dd) * D_ + lane * 4;
          __builtin_amdgcn_global_load_lds(
              (const __attribute__((address_space(1))) void*)g,
              (__attribute__((address_space(3))) void*)&wst[cur][dd][0], 16, 0, 0);
        }
        asm volatile("s_waitcnt vmcnt(8)" ::: "memory");   // next tile (own 8) done
      } else {
        asm volatile("s_waitcnt vmcnt(0)" ::: "memory");   // last prefetch: drain
      }
      __builtin_amdgcn_s_barrier();          // next buf globally ready
      __builtin_amdgcn_sched_barrier(0);
    }
  }

  // relu
  #pragma unroll
  for (int i = 0; i < RPW; ++i)
    #pragma unroll
    for (int c = 0; c < 4; ++c) acc[i][c] = fmaxf(acc[i][c], 0.f);

  f4 w2r[P_];
  #pragma unroll
  for (int p = 0; p < P_; ++p) w2r[p] = *(const f4*)(W2 + p * D_ + lane * 4);
  float b2r[P_];
  #pragma unroll
  for (int p = 0; p < P_; ++p) b2r[p] = b2[p];

  // epilogue in two 8-row halves (keeps v[] at 64 regs)
  for (int half = 0; half < 2; ++half) {
    float v[64];
    #pragma unroll
    for (int r = 0; r < 8; ++r)
      #pragma unroll
      for (int p = 0; p < P_; ++p) {
        f4 h = acc[half * 8 + r];
        v[r * 8 + p] = h[0]*w2r[p][0] + h[1]*w2r[p][1] + h[2]*w2r[p][2] + h[3]*w2r[p][3];
      }

    // split-butterfly: xor 1,2,4 halves the live set each step
    #pragma unroll
    for (int step = 0; step < 3; ++step) {
      const int s = 1 << step;
      const int hl = 32 >> step;
      const bool upper = (lane & s) != 0;
      #pragma unroll
      for (int i = 0; i < hl; ++i) {
        float a = v[i], b = v[i + hl];
        float send = upper ? a : b;
        float recv = __shfl_xor(send, s, 64);
        v[i] = (upper ? b : a) + recv;
      }
    }
    #pragma unroll
    for (int s = 8; s < 64; s <<= 1)
      #pragma unroll
      for (int i = 0; i < 8; ++i) v[i] += __shfl_xor(v[i], s, 64);

    if (lane < 8) {
      float best = v[0] + b2r[0];
      int am = 0;
      #pragma unroll
      for (int p = 1; p < P_; ++p) {
        float L = v[p] + b2r[p];
        if (L > best) { best = L; am = p; }
      }
      int r = ((lane & 1) << 2) | (lane & 2) | ((lane & 4) >> 2);
      dur[row0 + wave * RPW + half * 8 + r] = am;
    }
  }
}

// ---------------- kernel 2: per-batch shfl scan + scatter src ----------------
__global__ void k_scan(const int* __restrict__ dur, int* __restrict__ src, int mel) {
  __shared__ int wsum[8];
  int t = threadIdx.x, b = blockIdx.x;
  int lane = t & 63, wave = t >> 6;
  int d = dur[b * T_ + t];
  int v = d;
  #pragma unroll
  for (int s = 1; s < 64; s <<= 1) {
    int u = __shfl_up(v, s, 64);
    if (lane >= s) v += u;
  }
  if (lane == 63) wsum[wave] = v;
  __syncthreads();
  if (t == 0) {
    int run = 0;
    #pragma unroll
    for (int i = 0; i < 8; ++i) { run += wsum[i]; wsum[i] = run; }
  }
  __syncthreads();
  int cs = v + (wave ? wsum[wave - 1] : 0);
  int start = cs - d;
  int total = wsum[7];
  for (int m = start; m < cs; ++m) src[b * mel + m] = t;           // searchsorted right
  for (int m = total + t; m < mel; m += T_) src[b * mel + m] = -1; // masked tail
}

// ---------------- kernel 3: gather/expand ----------------
__global__ __launch_bounds__(256) void k_gather(
    const float* __restrict__ x, const int* __restrict__ src,
    float* __restrict__ out, int mel)
{
  int lane = threadIdx.x & 63;
  int wave = threadIdx.x >> 6;
  int m = blockIdx.x * 4 + wave;
  int b = blockIdx.y;
  if (m >= mel) return;
  int s = src[b * mel + m];
  f4 val = {0.f, 0.f, 0.f, 0.f};
  if (s >= 0) val = *(const f4*)(x + ((size_t)b * T_ + s) * D_ + lane * 4);
  *(f4*)(out + ((size_t)b * mel + m) * D_ + lane * 4) = val;
}

extern "C" void kernel_launch(void* const* d_in, const int* in_sizes, int n_in,
                              void* d_out, int out_size, void* d_ws, size_t ws_size,
                              hipStream_t stream) {
  const float* x  = (const float*)d_in[0];
  const float* W1 = (const float*)d_in[1];
  const float* b1 = (const float*)d_in[2];
  const float* W2 = (const float*)d_in[3];
  const float* b2 = (const float*)d_in[4];
  float* out = (float*)d_out;

  int mel = out_size / (B_ * D_);   // 3584

  float* w1t = (float*)d_ws;                                  // 256 KB
  int*   dur = (int*)((char*)d_ws + D_ * D_ * sizeof(float)); // 64 KB
  int*   src = dur + BT;                                      // B*mel*4 = 448 KB

  k_transpose<<<D_, D_, 0, stream>>>(W1, w1t);
  k_dur<<<BT / RPB, 256, 0, stream>>>(x, w1t, b1, W2, b2, dur);
  k_scan<<<B_, T_, 0, stream>>>(dur, src, mel);
  k_gather<<<dim3((mel + 3) / 4, B_), 256, 0, stream>>>(x, src, out, mel);
}

// Round 3
// 65.108 us; speedup vs baseline: 3.1220x; 3.1220x over previous
//
#include <hip/hip_runtime.h>

#define B_ 32
#define T_ 512
#define D_ 256
#define P_ 8
#define BT (B_*T_)
#define KT 32
#define NKT (D_/KT)
#define RPW 8            // rows per wave
#define RPB 32           // rows per block (4 waves)

typedef float f4 __attribute__((ext_vector_type(4)));

// ---------------- kernel 0: W1 [e][d] -> w1t [d][e] ----------------
__global__ void k_transpose(const float* __restrict__ W1, float* __restrict__ w1t) {
  int d = blockIdx.x;
  int e = threadIdx.x;
  w1t[d * D_ + e] = W1[e * D_ + d];
}

// ---------------- kernel 1: fused GEMM1 + GEMM2 + argmax -> dur ----------------
// 512 blocks x 256 threads (4 waves), 32 rows/block, 8 rows/wave.
// Double-buffered k-tiles (W + x-slice), ONE __syncthreads per tile.
// LDS = 64KB (W dbuf) + 8KB (x dbuf) = 72KB -> 2 blocks/CU, 8 waves/CU.
__global__ __launch_bounds__(256, 2) void k_dur(
    const float* __restrict__ x, const float* __restrict__ w1t,
    const float* __restrict__ b1, const float* __restrict__ W2,
    const float* __restrict__ b2, int* __restrict__ dur)
{
  __shared__ float wst[2][KT][D_];    // 64 KB: W1^T k-tile double buffer
  __shared__ float xst[2][RPB][KT];   // 8 KB: x k-slice double buffer

  const int tid  = threadIdx.x;
  const int lane = tid & 63;
  const int wave = tid >> 6;
  const int row0 = blockIdx.x * RPB;

  // ---- staging helpers (issued async; completion via the barrier's vmcnt drain)
  auto stage = [&](int kt, int buf) {
    // x k-slice: 8 rows x 32 floats per wave = 1KB = one global_load_lds
    {
      const float* g = x + (size_t)(row0 + wave * 8 + (lane >> 3)) * D_
                         + kt * KT + (lane & 7) * 4;
      __builtin_amdgcn_global_load_lds(
          (const __attribute__((address_space(1))) void*)g,
          (__attribute__((address_space(3))) void*)&xst[buf][wave * 8][0], 16, 0, 0);
    }
    // W k-tile: 8 rows per wave
    for (int i = 0; i < 8; ++i) {
      int dd = wave * 8 + i;
      const float* g = w1t + (size_t)(kt * KT + dd) * D_ + lane * 4;
      __builtin_amdgcn_global_load_lds(
          (const __attribute__((address_space(1))) void*)g,
          (__attribute__((address_space(3))) void*)&wst[buf][dd][0], 16, 0, 0);
    }
  };

  stage(0, 0);
  __syncthreads();

  f4 b1v = *(const f4*)(b1 + lane * 4);
  f4 acc[RPW];
  #pragma unroll
  for (int i = 0; i < RPW; ++i) acc[i] = b1v;

  for (int kt = 0; kt < NKT; ++kt) {
    const int cur = kt & 1;
    if (kt + 1 < NKT) stage(kt + 1, cur ^ 1);   // prefetch under compute

    f4 loc[RPW];   // per-k-tile partials: summation order identical to R1's pass
    #pragma unroll
    for (int i = 0; i < RPW; ++i) loc[i] = (f4){0.f, 0.f, 0.f, 0.f};

    #pragma unroll
    for (int dq = 0; dq < KT / 4; ++dq) {
      f4 wv[4];
      #pragma unroll
      for (int j = 0; j < 4; ++j) wv[j] = *(const f4*)&wst[cur][dq * 4 + j][lane * 4];
      #pragma unroll
      for (int i = 0; i < RPW; ++i) {
        f4 xv = *(const f4*)&xst[cur][wave * 8 + i][dq * 4];  // wave-uniform broadcast
        loc[i] += xv.x * wv[0];
        loc[i] += xv.y * wv[1];
        loc[i] += xv.z * wv[2];
        loc[i] += xv.w * wv[3];
      }
    }
    #pragma unroll
    for (int i = 0; i < RPW; ++i) acc[i] += loc[i];

    __syncthreads();   // drains this wave's gl_lds (vmcnt) + joins waves
  }

  // relu
  #pragma unroll
  for (int i = 0; i < RPW; ++i)
    #pragma unroll
    for (int c = 0; c < 4; ++c) acc[i][c] = fmaxf(acc[i][c], 0.f);

  // GEMM2 partials: lane's 4 e's vs all 8 W2 rows
  f4 w2r[P_];
  #pragma unroll
  for (int p = 0; p < P_; ++p) w2r[p] = *(const f4*)(W2 + p * D_ + lane * 4);
  float b2r[P_];
  #pragma unroll
  for (int p = 0; p < P_; ++p) b2r[p] = b2[p];

  float v[64];
  #pragma unroll
  for (int r = 0; r < 8; ++r)
    #pragma unroll
    for (int p = 0; p < P_; ++p) {
      f4 h = acc[r];
      v[r * 8 + p] = h[0]*w2r[p][0] + h[1]*w2r[p][1] + h[2]*w2r[p][2] + h[3]*w2r[p][3];
    }

  // split-butterfly: xor 1,2,4 halves the live value set each step
  #pragma unroll
  for (int step = 0; step < 3; ++step) {
    const int s = 1 << step;
    const int hl = 32 >> step;
    const bool upper = (lane & s) != 0;
    #pragma unroll
    for (int i = 0; i < hl; ++i) {
      float a = v[i], b = v[i + hl];
      float send = upper ? a : b;
      float recv = __shfl_xor(send, s, 64);
      v[i] = (upper ? b : a) + recv;
    }
  }
  #pragma unroll
  for (int s = 8; s < 64; s <<= 1)
    #pragma unroll
    for (int i = 0; i < 8; ++i) v[i] += __shfl_xor(v[i], s, 64);

  if (lane < 8) {
    float best = v[0] + b2r[0];
    int am = 0;
    #pragma unroll
    for (int p = 1; p < P_; ++p) {
      float L = v[p] + b2r[p];
      if (L > best) { best = L; am = p; }
    }
    int r = ((lane & 1) << 2) | (lane & 2) | ((lane & 4) >> 2);
    dur[row0 + wave * 8 + r] = am;
  }
}

// ---------------- kernel 2: per-batch shfl scan + scatter src ----------------
__global__ void k_scan(const int* __restrict__ dur, int* __restrict__ src, int mel) {
  __shared__ int wsum[8];
  int t = threadIdx.x, b = blockIdx.x;
  int lane = t & 63, wave = t >> 6;
  int d = dur[b * T_ + t];
  int v = d;
  #pragma unroll
  for (int s = 1; s < 64; s <<= 1) {
    int u = __shfl_up(v, s, 64);
    if (lane >= s) v += u;
  }
  if (lane == 63) wsum[wave] = v;
  __syncthreads();
  if (t == 0) {
    int run = 0;
    #pragma unroll
    for (int i = 0; i < 8; ++i) { run += wsum[i]; wsum[i] = run; }
  }
  __syncthreads();
  int cs = v + (wave ? wsum[wave - 1] : 0);
  int start = cs - d;
  int total = wsum[7];
  for (int m = start; m < cs; ++m) src[b * mel + m] = t;           // searchsorted right
  for (int m = total + t; m < mel; m += T_) src[b * mel + m] = -1; // masked tail
}

// ---------------- kernel 3: gather/expand ----------------
__global__ __launch_bounds__(256) void k_gather(
    const float* __restrict__ x, const int* __restrict__ src,
    float* __restrict__ out, int mel)
{
  int lane = threadIdx.x & 63;
  int wave = threadIdx.x >> 6;
  int m = blockIdx.x * 4 + wave;
  int b = blockIdx.y;
  if (m >= mel) return;
  int s = src[b * mel + m];
  f4 val = {0.f, 0.f, 0.f, 0.f};
  if (s >= 0) val = *(const f4*)(x + ((size_t)b * T_ + s) * D_ + lane * 4);
  *(f4*)(out + ((size_t)b * mel + m) * D_ + lane * 4) = val;
}

extern "C" void kernel_launch(void* const* d_in, const int* in_sizes, int n_in,
                              void* d_out, int out_size, void* d_ws, size_t ws_size,
                              hipStream_t stream) {
  const float* x  = (const float*)d_in[0];
  const float* W1 = (const float*)d_in[1];
  const float* b1 = (const float*)d_in[2];
  const float* W2 = (const float*)d_in[3];
  const float* b2 = (const float*)d_in[4];
  float* out = (float*)d_out;

  int mel = out_size / (B_ * D_);   // 3584

  float* w1t = (float*)d_ws;                                  // 256 KB
  int*   dur = (int*)((char*)d_ws + D_ * D_ * sizeof(float)); // 64 KB
  int*   src = dur + BT;                                      // B*mel*4 = 448 KB

  k_transpose<<<D_, D_, 0, stream>>>(W1, w1t);
  k_dur<<<BT / RPB, 256, 0, stream>>>(x, w1t, b1, W2, b2, dur);
  k_scan<<<B_, T_, 0, stream>>>(dur, src, mel);
  k_gather<<<dim3((mel + 3) / 4, B_), 256, 0, stream>>>(x, src, out, mel);
}